// Round 2
// baseline (443.536 us; speedup 1.0000x reference)
//
#include <hip/hip_runtime.h>

// Inception Temporal Layer: 3 causal VALID conv1d stages + leaky_relu(0.01),
// N = 8192 independent rows, keep first 48 outputs of each scale.
// Shapes: x[8192][512][4] f32; w1[16][4][6]; w2[16][16][4]; w3[16][16][13];
// out[8192][3][48][16] f32.
//
// Dependency cone (only t<48 of each scale survives):
//   o3[t<48] needs o2[0..142]; o2 needs o1[0..148]; o1 needs x[0..449].

#define LREL(v) ((v) > 0.0f ? (v) : 0.01f * (v))

__global__ __launch_bounds__(256, 2) void itl_kernel(
    const float* __restrict__ x,    // [8192][512][4]
    const float* __restrict__ w1,   // [16][4][6]
    const float* __restrict__ b1,   // [16]
    const float* __restrict__ w2,   // [16][16][4]
    const float* __restrict__ b2,   // [16]
    const float* __restrict__ w3,   // [16][16][13]
    const float* __restrict__ b3,   // [16]
    float* __restrict__ out)        // [8192][3][48][16]
{
    __shared__ float w1s[384];    // [(c*6+k)*16 + co]
    __shared__ float w2s[1024];   // [(ci*4+k)*16 + co]
    __shared__ float w3s[3328];   // [(ci*13+k)*16 + co]
    __shared__ float bs[48];
    __shared__ float xs[4][512];  // x transposed: [c][t]
    __shared__ float o1s[16][152];// [co][t], t<149 valid
    __shared__ float o2s[16][144];// [co][t], t<143 valid

    const int tid = threadIdx.x;
    const int n   = blockIdx.x;
    const int co  = tid & 15;
    const int tg  = tid >> 4;

    // ---- stage weights into LDS, transposed so co is the contiguous dim ----
    // NOTE: block has 256 threads — every staging loop must stride by 256.
    for (int t = tid; t < 384; t += 256)  { int o = t / 24,  r = t % 24;  w1s[r * 16 + o] = w1[t]; }
    if (tid < 16)       bs[tid] = b1[tid];
    else if (tid < 32)  bs[tid] = b2[tid - 16];
    else if (tid < 48)  bs[tid] = b3[tid - 32];
    for (int t = tid; t < 1024; t += 256) { int o = t >> 6,  r = t & 63;  w2s[r * 16 + o] = w2[t]; }
    for (int t = tid; t < 3328; t += 256) { int o = t / 208, r = t % 208; w3s[r * 16 + o] = w3[t]; }

    // ---- stage x into LDS transposed: one float4 per t (Cin=4 contiguous) ----
    const float4* x4 = reinterpret_cast<const float4*>(x) + (size_t)n * 512;
    for (int t = tid; t < 512; t += 256) {
        float4 v = x4[t];
        xs[0][t] = v.x; xs[1][t] = v.y; xs[2][t] = v.z; xs[3][t] = v.w;
    }
    __syncthreads();

    float* outn = out + (size_t)n * 2304;

    // ---- stage 1: o1[t][co] = leaky(sum_{c<4,k<6} x[3t+k][c]*w1[co][c][k] + b1) ----
    // thread owns t = tg*10 + r, r<10 (covers 0..159, valid t<149)
    {
        float acc[10];
        #pragma unroll
        for (int r = 0; r < 10; ++r) acc[r] = bs[co];
        #pragma unroll
        for (int c = 0; c < 4; ++c) {
            float xin[33];  // x positions 30*tg .. 30*tg+32 (max 482 < 512)
            #pragma unroll
            for (int i = 0; i < 33; ++i) xin[i] = xs[c][30 * tg + i];
            #pragma unroll
            for (int k = 0; k < 6; ++k) {
                float w = w1s[(c * 6 + k) * 16 + co];
                #pragma unroll
                for (int r = 0; r < 10; ++r) acc[r] = fmaf(xin[3 * r + k], w, acc[r]);
            }
        }
        #pragma unroll
        for (int r = 0; r < 10; ++r) {
            int t = tg * 10 + r;
            float v = LREL(acc[r]);
            if (t < 149) o1s[co][t] = v;
            if (t < 48)  outn[t * 16 + co] = v;   // scale 0
        }
    }
    __syncthreads();

    // ---- stage 2: o2[j][co] = leaky(sum_{ci<16,k<4} o1[j+2k][ci]*w2[co][ci][k] + b2) ----
    // thread owns j = tg*9 + r, r<9 (covers 0..143, valid j<143)
    {
        float acc[9];
        #pragma unroll
        for (int r = 0; r < 9; ++r) acc[r] = bs[16 + co];
        for (int ci = 0; ci < 16; ++ci) {
            float xin[15];  // o1 positions 9*tg .. 9*tg+14 (max 149; index 149 only
                            // feeds the discarded j=143 accumulator)
            #pragma unroll
            for (int i = 0; i < 15; ++i) xin[i] = o1s[ci][9 * tg + i];
            #pragma unroll
            for (int k = 0; k < 4; ++k) {
                float w = w2s[(ci * 4 + k) * 16 + co];
                #pragma unroll
                for (int r = 0; r < 9; ++r) acc[r] = fmaf(xin[r + 2 * k], w, acc[r]);
            }
        }
        #pragma unroll
        for (int r = 0; r < 9; ++r) {
            int j = tg * 9 + r;
            float v = LREL(acc[r]);
            if (j < 143) o2s[co][j] = v;
            if (j < 48)  outn[768 + j * 16 + co] = v;  // scale 1
        }
    }
    __syncthreads();

    // ---- stage 3: o3[t][co] = leaky(sum_{ci<16,k<13} o2[2t+4k][ci]*w3[co][ci][k] + b3) ----
    // thread owns t = tg*3 + r, r<3 (exactly 48)
    {
        float acc[3];
        #pragma unroll
        for (int r = 0; r < 3; ++r) acc[r] = bs[32 + co];
        for (int ci = 0; ci < 16; ++ci) {
            float xin[27];  // even o2 positions 6*tg + 2m, m<27 (max 142 < 144)
            #pragma unroll
            for (int m = 0; m < 27; ++m) xin[m] = o2s[ci][6 * tg + 2 * m];
            #pragma unroll
            for (int k = 0; k < 13; ++k) {
                float w = w3s[(ci * 13 + k) * 16 + co];
                #pragma unroll
                for (int r = 0; r < 3; ++r) acc[r] = fmaf(xin[r + 2 * k], w, acc[r]);
            }
        }
        #pragma unroll
        for (int r = 0; r < 3; ++r) {
            int t = tg * 3 + r;
            outn[1536 + t * 16 + co] = LREL(acc[r]);  // scale 2
        }
    }
}

extern "C" void kernel_launch(void* const* d_in, const int* in_sizes, int n_in,
                              void* d_out, int out_size, void* d_ws, size_t ws_size,
                              hipStream_t stream) {
    const float* x  = (const float*)d_in[0];
    const float* w1 = (const float*)d_in[1];
    const float* b1 = (const float*)d_in[2];
    const float* w2 = (const float*)d_in[3];
    const float* b2 = (const float*)d_in[4];
    const float* w3 = (const float*)d_in[5];
    const float* b3 = (const float*)d_in[6];
    float* out = (float*)d_out;

    const int N = 16 * 64 * 8;  // 8192 independent rows
    itl_kernel<<<N, 256, 0, stream>>>(x, w1, b1, w2, b2, w3, b3, out);
}